// Round 12
// baseline (955.446 us; speedup 1.0000x reference)
//
#include <hip/hip_runtime.h>

// Fully-fused CIN (16x16x32 MFMA, HW-verified layouts).
//   Y_hh[o,d] = sum_m W[o,hh,m] * x0[b,m,d]      (MFMA, 3-term bf16 split)
//   h_next[o,d] = relu(bias[o] + sum_hh h[hh,d] * Y_hh[o,d])
// Round-11: software-pipelined y. Round-9/11 evidence: 4 waves/SIMD resident
// but MfmaUtil stuck at 53% — per-wave in-order issue serialized {12 MFMA ->
// wait y-chain -> 16 acc-FMA}; MFMA and VALU were additive. Now body(hh) =
// {MFMAs for hh into yC} then {acc-FMAs for hh-1 from yP (long complete)} ->
// the matrix pipe is fed during every VALU tail. A-ring depth 2 (VGPR room),
// power-of-2 wrap replaces clamp selects (HW = 16/64).
// B=512, M=32, D=64, O=128/layer, H = 32/128/128.

constexpr int Bb = 512, Mm = 32, Dd = 64, Oo = 128;

typedef __attribute__((ext_vector_type(8))) short bf16x8;
typedef __attribute__((ext_vector_type(4))) float f32x4;

static __device__ __forceinline__ ushort f2bf(float f) {
  union { float f; uint u; } v;
  v.f = f;
  uint u = v.u;
  return (ushort)((u + 0x7FFFu + ((u >> 16) & 1u)) >> 16);  // RNE
}
static __device__ __forceinline__ float bf2f(ushort b) {
  union { uint u; float f; } v;
  v.u = (uint)b << 16;
  return v.f;
}

// W[o][hh*32+m] -> A-frag planes [hh][f][lane][j]: o=f*16+(lane&15), m=(lane>>4)*8+j
static __device__ __forceinline__ void wsplit_one(const float* __restrict__ W,
                                                  ushort* __restrict__ Whi,
                                                  ushort* __restrict__ Wlo,
                                                  int H, int t) {
  int l = t & 63, fo = (t >> 6) & 7, hh = t >> 9;
  int o = fo * 16 + (l & 15);
  int m0 = (l >> 4) * 8;
  const float* src = W + (size_t)o * (H * 32) + hh * 32 + m0;
  ushort hi[8], lo[8];
#pragma unroll
  for (int j = 0; j < 8; ++j) {
    float w = src[j];
    ushort h = f2bf(w);
    hi[j] = h;
    lo[j] = f2bf(w - bf2f(h));
  }
  *reinterpret_cast<uint4*>(Whi + (size_t)t * 8) = *reinterpret_cast<uint4*>(hi);
  *reinterpret_cast<uint4*>(Wlo + (size_t)t * 8) = *reinterpret_cast<uint4*>(lo);
}

// x0[b][m][d] -> B-frag planes [b][fd][lane][j]: m=(lane>>4)*8+j, d=fd*16+(lane&15)
static __device__ __forceinline__ void x0split_one(const float* __restrict__ x0,
                                                   ushort* __restrict__ Xhi,
                                                   ushort* __restrict__ Xlo, int t) {
  int l = t & 63, fd = (t >> 6) & 3, b = t >> 8;
  int d = fd * 16 + (l & 15);
  int m0 = (l >> 4) * 8;
  const float* src = x0 + ((size_t)b * Mm + m0) * Dd + d;
  ushort hi[8], lo[8];
#pragma unroll
  for (int j = 0; j < 8; ++j) {
    float w = src[j * Dd];
    ushort h = f2bf(w);
    hi[j] = h;
    lo[j] = f2bf(w - bf2f(h));
  }
  *reinterpret_cast<uint4*>(Xhi + (size_t)t * 8) = *reinterpret_cast<uint4*>(hi);
  *reinterpret_cast<uint4*>(Xlo + (size_t)t * 8) = *reinterpret_cast<uint4*>(lo);
}

__global__ __launch_bounds__(256) void prep_kernel(
    const float* __restrict__ W0, const float* __restrict__ W1,
    const float* __restrict__ W2, const float* __restrict__ x0,
    ushort* __restrict__ Whi0, ushort* __restrict__ Wlo0,
    ushort* __restrict__ Whi1, ushort* __restrict__ Wlo1,
    ushort* __restrict__ Whi2, ushort* __restrict__ Wlo2,
    ushort* __restrict__ Xhi, ushort* __restrict__ Xlo) {
  int t = blockIdx.x * 256 + threadIdx.x;
  if (t < 16384) {
    wsplit_one(W0, Whi0, Wlo0, 32, t);
  } else if (t < 81920) {
    wsplit_one(W1, Whi1, Wlo1, 128, t - 16384);
  } else if (t < 147456) {
    wsplit_one(W2, Whi2, Wlo2, 128, t - 81920);
  } else {
    x0split_one(x0, Xhi, Xlo, t - 147456);
  }
}

// Software-pipelined MFMA loop over HW hh-steps (this wave's K-half).
// body(hh): issue 12 MFMAs for step hh -> yC; acc-update step hh-1 from yP.
template <int HW>
static __device__ __forceinline__ void mfma_loop(
    const float* __restrict__ hsrc,
    const ushort* __restrict__ pwh, const ushort* __restrict__ pwl,
    const bf16x8 (&xh)[4], const bf16x8 (&xl)[4], int cid, f32x4 (&acc)[4]) {
  static_assert((HW & (HW - 1)) == 0 && HW >= 8, "HW must be pow2 >= 8");
  const size_t hstride = (size_t)8 * 64 * 8;  // ushorts per hh
  const f32x4 kZ = {0.f, 0.f, 0.f, 0.f};

  // A-ring depth 2
  bf16x8 Ah[2], Al[2];
  Ah[0] = *reinterpret_cast<const bf16x8*>(pwh);
  Al[0] = *reinterpret_cast<const bf16x8*>(pwl);
  Ah[1] = *reinterpret_cast<const bf16x8*>(pwh + hstride);
  Al[1] = *reinterpret_cast<const bf16x8*>(pwl + hstride);

  float hvP[4];  // h for the acc-target step (hh-1)
#pragma unroll
  for (int fd = 0; fd < 4; ++fd) hvP[fd] = hsrc[fd * 16 + cid];

  // prologue: y for hh=0
  f32x4 yP[4], yC[4];
#pragma unroll
  for (int fd = 0; fd < 4; ++fd)
    yP[fd] = __builtin_amdgcn_mfma_f32_16x16x32_bf16(Ah[0], xh[fd], kZ, 0, 0, 0);
#pragma unroll
  for (int fd = 0; fd < 4; ++fd)
    yP[fd] = __builtin_amdgcn_mfma_f32_16x16x32_bf16(Ah[0], xl[fd], yP[fd], 0, 0, 0);
#pragma unroll
  for (int fd = 0; fd < 4; ++fd)
    yP[fd] = __builtin_amdgcn_mfma_f32_16x16x32_bf16(Al[0], xh[fd], yP[fd], 0, 0, 0);
  // refill slot 0 with hh=2
  Ah[0] = *reinterpret_cast<const bf16x8*>(pwh + 2 * hstride);
  Al[0] = *reinterpret_cast<const bf16x8*>(pwl + 2 * hstride);

  // one pipelined step: MFMAs for hh, then acc for hh-1
#define CIN_STEP(hh_expr, slot)                                                     \
  {                                                                                 \
    const int hh_ = (hh_expr);                                                      \
    _Pragma("unroll") for (int fd = 0; fd < 4; ++fd) yC[fd] =                       \
        __builtin_amdgcn_mfma_f32_16x16x32_bf16(Ah[slot], xh[fd], kZ, 0, 0, 0);     \
    _Pragma("unroll") for (int fd = 0; fd < 4; ++fd) yC[fd] =                       \
        __builtin_amdgcn_mfma_f32_16x16x32_bf16(Ah[slot], xl[fd], yC[fd], 0, 0, 0); \
    _Pragma("unroll") for (int fd = 0; fd < 4; ++fd) yC[fd] =                       \
        __builtin_amdgcn_mfma_f32_16x16x32_bf16(Al[slot], xh[fd], yC[fd], 0, 0, 0); \
    const size_t roff = (size_t)((hh_ + 2) & (HW - 1)) * hstride;                   \
    Ah[slot] = *reinterpret_cast<const bf16x8*>(pwh + roff);                        \
    Al[slot] = *reinterpret_cast<const bf16x8*>(pwl + roff);                        \
    float hvN[4];                                                                   \
    _Pragma("unroll") for (int fd = 0; fd < 4; ++fd) hvN[fd] =                      \
        hsrc[hh_ * 64 + fd * 16 + cid];                                             \
    _Pragma("unroll") for (int fd = 0; fd < 4; ++fd)                                \
        _Pragma("unroll") for (int r = 0; r < 4; ++r)                               \
            acc[fd][r] = fmaf(hvP[fd], yP[fd][r], acc[fd][r]);                      \
    _Pragma("unroll") for (int fd = 0; fd < 4; ++fd) hvP[fd] = hvN[fd];             \
    _Pragma("unroll") for (int fd = 0; fd < 4; ++fd) yP[fd] = yC[fd];               \
  }

  // peeled group g=0: steps 1..3
  CIN_STEP(1, 1)
  CIN_STEP(2, 0)
  CIN_STEP(3, 1)

#pragma unroll 1
  for (int g = 1; g < HW / 4; ++g) {
    const int h0 = g * 4;
    CIN_STEP(h0 + 0, 0)
    CIN_STEP(h0 + 1, 1)
    CIN_STEP(h0 + 2, 0)
    CIN_STEP(h0 + 3, 1)
  }
#undef CIN_STEP

  // epilogue: acc-update for hh = HW-1
#pragma unroll
  for (int fd = 0; fd < 4; ++fd)
#pragma unroll
    for (int r = 0; r < 4; ++r) acc[fd][r] = fmaf(hvP[fd], yP[fd][r], acc[fd][r]);
}

// One layer: both k-half waves run mfma_loop over their range; kh=1 dumps raw
// acc into h_next's f-region; kh=0 combines, applies bias+relu, writes h_next
// (unless !WRITE_H) and folds the d-sum into score.
template <int H, bool WRITE_H>
static __device__ __forceinline__ void layer(
    const float* __restrict__ h_src, float* __restrict__ h_next,
    const ushort* __restrict__ Whi, const ushort* __restrict__ Wlo,
    const float* __restrict__ bias, const float* __restrict__ lw,
    const bf16x8 (&xh)[4], const bf16x8 (&xl)[4],
    int f, int kh, int lane, float& score) {
  const int cid = lane & 15;
  const int rg = lane >> 4;
  const int hh0 = kh * (H / 2);

  f32x4 acc[4];
#pragma unroll
  for (int fd = 0; fd < 4; ++fd) acc[fd] = (f32x4){0.f, 0.f, 0.f, 0.f};

  const ushort* pwh = Whi + (((size_t)hh0 * 8 + f) * 64 + lane) * 8;
  const ushort* pwl = Wlo + (((size_t)hh0 * 8 + f) * 64 + lane) * 8;
  mfma_loop<H / 2>(h_src + hh0 * 64, pwh, pwl, xh, xl, cid, acc);

  if (kh) {  // dump raw partial acc into h_next's f-region (dead until combine)
#pragma unroll
    for (int r = 0; r < 4; ++r)
#pragma unroll
      for (int fd = 0; fd < 4; ++fd)
        h_next[(f * 16 + rg * 4 + r) * 64 + fd * 16 + cid] = acc[fd][r];
  }
  __syncthreads();
  if (!kh) {
#pragma unroll
    for (int r = 0; r < 4; ++r) {
      const int o = f * 16 + rg * 4 + r;
      const float bs = bias[o];
      float sd = 0.f;
#pragma unroll
      for (int fd = 0; fd < 4; ++fd) {
        float v = acc[fd][r] + h_next[o * 64 + fd * 16 + cid] + bs;
        v = v > 0.f ? v : 0.f;
        if (WRITE_H) h_next[o * 64 + fd * 16 + cid] = v;
        sd += v;
      }
#pragma unroll
      for (int mk = 1; mk < 16; mk <<= 1) sd += __shfl_xor(sd, mk, 64);
      if (cid == 0) score = fmaf(sd, lw[o], score);
    }
  }
  __syncthreads();
}

__global__ __launch_bounds__(1024, 4) void cin_fused_kernel(
    const float* __restrict__ x0,
    const ushort* __restrict__ Whi0, const ushort* __restrict__ Wlo0,
    const ushort* __restrict__ Whi1, const ushort* __restrict__ Wlo1,
    const ushort* __restrict__ Whi2, const ushort* __restrict__ Wlo2,
    const ushort* __restrict__ Xhi, const ushort* __restrict__ Xlo,
    const float* __restrict__ b0, const float* __restrict__ b1,
    const float* __restrict__ b2, const float* __restrict__ lw,
    const float* __restrict__ lb, float* __restrict__ out) {
  __shared__ float hA[Oo * Dd];  // 32 KB: x0 (L0 in), then L1 out (L2 in)
  __shared__ float hB[Oo * Dd];  // 32 KB: L0 out (L1 in), then L2 scratch+sred
  // total LDS = 65536 B

  const int b = blockIdx.x;
  const int t = threadIdx.x;
  const int lane = t & 63;
  const int w = __builtin_amdgcn_readfirstlane(t >> 6);  // 16 waves
  const int f = w & 7;    // o-frag
  const int kh = w >> 3;  // k-half

  // x0 B-fragments, register-resident throughout
  bf16x8 xh[4], xl[4];
#pragma unroll
  for (int fd = 0; fd < 4; ++fd) {
    size_t off = (((size_t)b * 4 + fd) * 64 + lane) * 8;
    xh[fd] = *reinterpret_cast<const bf16x8*>(Xhi + off);
    xl[fd] = *reinterpret_cast<const bf16x8*>(Xlo + off);
  }

  // stage x0[b] (32x64 f32 = 512 float4) into hA
  if (t < 512)
    reinterpret_cast<float4*>(hA)[t] =
        reinterpret_cast<const float4*>(x0 + (size_t)b * Mm * Dd)[t];
  __syncthreads();

  float score = 0.f;
  layer<32, true>(hA, hB, Whi0, Wlo0, b0, lw, xh, xl, f, kh, lane, score);
  layer<128, true>(hB, hA, Whi1, Wlo1, b1, lw + 128, xh, xl, f, kh, lane, score);
  layer<128, false>(hA, hB, Whi2, Wlo2, b2, lw + 256, xh, xl, f, kh, lane, score);

  // block-wide score reduction (hB scratch dead; layer() ended with a barrier)
#pragma unroll
  for (int mk = 1; mk < 64; mk <<= 1) score += __shfl_xor(score, mk, 64);
  if (lane == 0 && kh == 0) hB[f] = score;
  __syncthreads();
  if (t == 0) {
    float tot = 0.f;
#pragma unroll
    for (int i = 0; i < 8; ++i) tot += hB[i];
    out[b] = tot + lb[0];
  }
}

extern "C" void kernel_launch(void* const* d_in, const int* in_sizes, int n_in,
                              void* d_out, int out_size, void* d_ws, size_t ws_size,
                              hipStream_t stream) {
  const float* x0 = (const float*)d_in[0];
  const float* W0 = (const float*)d_in[1];
  const float* b0 = (const float*)d_in[2];
  const float* W1 = (const float*)d_in[3];
  const float* b1 = (const float*)d_in[4];
  const float* W2 = (const float*)d_in[5];
  const float* b2 = (const float*)d_in[6];
  const float* lw = (const float*)d_in[7];
  const float* lb = (const float*)d_in[8];
  float* out = (float*)d_out;

  // workspace: only the split planes
  ushort* Whi0 = (ushort*)d_ws;
  ushort* Wlo0 = Whi0 + (size_t)32 * 8 * 64 * 8;
  ushort* Whi1 = Wlo0 + (size_t)32 * 8 * 64 * 8;
  ushort* Wlo1 = Whi1 + (size_t)128 * 8 * 64 * 8;
  ushort* Whi2 = Wlo1 + (size_t)128 * 8 * 64 * 8;
  ushort* Wlo2 = Whi2 + (size_t)128 * 8 * 64 * 8;
  ushort* Xhi = Wlo2 + (size_t)128 * 8 * 64 * 8;
  ushort* Xlo = Xhi + (size_t)Bb * 4 * 64 * 8;

  prep_kernel<<<dim3(1088), dim3(256), 0, stream>>>(W0, W1, W2, x0, Whi0, Wlo0,
                                                    Whi1, Wlo1, Whi2, Wlo2, Xhi, Xlo);

  cin_fused_kernel<<<dim3(Bb), dim3(1024), 0, stream>>>(
      x0, Whi0, Wlo0, Whi1, Wlo1, Whi2, Wlo2, Xhi, Xlo, b0, b1, b2, lw, lb, out);
}

// Round 13
// 949.553 us; speedup vs baseline: 1.0062x; 1.0062x over previous
//
#include <hip/hip_runtime.h>

// Fully-fused CIN (16x16x32 MFMA, HW-verified layouts).
//   Y_hh[o,d] = sum_m W[o,hh,m] * x0[b,m,d]      (MFMA, 3-term bf16 split)
//   h_next[o,d] = relu(bias[o] + sum_hh h[hh,d] * Y_hh[o,d])
// Round-12: round-11's software-pipelined y, with the register budget fixed.
// Round-11 failed because __launch_bounds__(1024,4) = 4 blocks/CU -> 64-VGPR
// cap -> the y double-buffer spilled (1.4GB fetch / 1.0GB write of scratch).
// A 1024-thread block implies 16 waves resident -> VGPR <= 128 automatically;
// plain __launch_bounds__(1024) gives the full 128 budget. y ping-pongs by
// step parity (no copy): step hh computes y[hh&1], accumulates y[1-(hh&1)].
// B=512, M=32, D=64, O=128/layer, H = 32/128/128.

constexpr int Bb = 512, Mm = 32, Dd = 64, Oo = 128;

typedef __attribute__((ext_vector_type(8))) short bf16x8;
typedef __attribute__((ext_vector_type(4))) float f32x4;

static __device__ __forceinline__ ushort f2bf(float f) {
  union { float f; uint u; } v;
  v.f = f;
  uint u = v.u;
  return (ushort)((u + 0x7FFFu + ((u >> 16) & 1u)) >> 16);  // RNE
}
static __device__ __forceinline__ float bf2f(ushort b) {
  union { uint u; float f; } v;
  v.u = (uint)b << 16;
  return v.f;
}

// W[o][hh*32+m] -> A-frag planes [hh][f][lane][j]: o=f*16+(lane&15), m=(lane>>4)*8+j
static __device__ __forceinline__ void wsplit_one(const float* __restrict__ W,
                                                  ushort* __restrict__ Whi,
                                                  ushort* __restrict__ Wlo,
                                                  int H, int t) {
  int l = t & 63, fo = (t >> 6) & 7, hh = t >> 9;
  int o = fo * 16 + (l & 15);
  int m0 = (l >> 4) * 8;
  const float* src = W + (size_t)o * (H * 32) + hh * 32 + m0;
  ushort hi[8], lo[8];
#pragma unroll
  for (int j = 0; j < 8; ++j) {
    float w = src[j];
    ushort h = f2bf(w);
    hi[j] = h;
    lo[j] = f2bf(w - bf2f(h));
  }
  *reinterpret_cast<uint4*>(Whi + (size_t)t * 8) = *reinterpret_cast<uint4*>(hi);
  *reinterpret_cast<uint4*>(Wlo + (size_t)t * 8) = *reinterpret_cast<uint4*>(lo);
}

// x0[b][m][d] -> B-frag planes [b][fd][lane][j]: m=(lane>>4)*8+j, d=fd*16+(lane&15)
static __device__ __forceinline__ void x0split_one(const float* __restrict__ x0,
                                                   ushort* __restrict__ Xhi,
                                                   ushort* __restrict__ Xlo, int t) {
  int l = t & 63, fd = (t >> 6) & 3, b = t >> 8;
  int d = fd * 16 + (l & 15);
  int m0 = (l >> 4) * 8;
  const float* src = x0 + ((size_t)b * Mm + m0) * Dd + d;
  ushort hi[8], lo[8];
#pragma unroll
  for (int j = 0; j < 8; ++j) {
    float w = src[j * Dd];
    ushort h = f2bf(w);
    hi[j] = h;
    lo[j] = f2bf(w - bf2f(h));
  }
  *reinterpret_cast<uint4*>(Xhi + (size_t)t * 8) = *reinterpret_cast<uint4*>(hi);
  *reinterpret_cast<uint4*>(Xlo + (size_t)t * 8) = *reinterpret_cast<uint4*>(lo);
}

__global__ __launch_bounds__(256) void prep_kernel(
    const float* __restrict__ W0, const float* __restrict__ W1,
    const float* __restrict__ W2, const float* __restrict__ x0,
    ushort* __restrict__ Whi0, ushort* __restrict__ Wlo0,
    ushort* __restrict__ Whi1, ushort* __restrict__ Wlo1,
    ushort* __restrict__ Whi2, ushort* __restrict__ Wlo2,
    ushort* __restrict__ Xhi, ushort* __restrict__ Xlo) {
  int t = blockIdx.x * 256 + threadIdx.x;
  if (t < 16384) {
    wsplit_one(W0, Whi0, Wlo0, 32, t);
  } else if (t < 81920) {
    wsplit_one(W1, Whi1, Wlo1, 128, t - 16384);
  } else if (t < 147456) {
    wsplit_one(W2, Whi2, Wlo2, 128, t - 81920);
  } else {
    x0split_one(x0, Xhi, Xlo, t - 147456);
  }
}

// Software-pipelined MFMA loop over HW hh-steps (this wave's K-half).
// Step hh: issue 12 MFMAs for hh into y<p> (p = hh&1); acc-update hh-1 from
// y<1-p> (completed one full step ago -> no wait on the MFMA chain).
template <int HW>
static __device__ __forceinline__ void mfma_loop(
    const float* __restrict__ hsrc,
    const ushort* __restrict__ pwh, const ushort* __restrict__ pwl,
    const bf16x8 (&xh)[4], const bf16x8 (&xl)[4], int cid, f32x4 (&acc)[4]) {
  static_assert((HW & (HW - 1)) == 0 && HW >= 8, "HW must be pow2 >= 8");
  const size_t hstride = (size_t)8 * 64 * 8;  // ushorts per hh
  const f32x4 kZ = {0.f, 0.f, 0.f, 0.f};

  // A-ring depth 2 (slot = hh&1, refilled 2 ahead)
  bf16x8 Ah[2], Al[2];
  Ah[0] = *reinterpret_cast<const bf16x8*>(pwh);
  Al[0] = *reinterpret_cast<const bf16x8*>(pwl);
  Ah[1] = *reinterpret_cast<const bf16x8*>(pwh + hstride);
  Al[1] = *reinterpret_cast<const bf16x8*>(pwl + hstride);

  float hvP[4];  // h for the acc-target step (hh-1)
#pragma unroll
  for (int fd = 0; fd < 4; ++fd) hvP[fd] = hsrc[fd * 16 + cid];

  f32x4 y0[4], y1[4];
  // prologue: y for hh=0 into y0
#pragma unroll
  for (int fd = 0; fd < 4; ++fd)
    y0[fd] = __builtin_amdgcn_mfma_f32_16x16x32_bf16(Ah[0], xh[fd], kZ, 0, 0, 0);
#pragma unroll
  for (int fd = 0; fd < 4; ++fd)
    y0[fd] = __builtin_amdgcn_mfma_f32_16x16x32_bf16(Ah[0], xl[fd], y0[fd], 0, 0, 0);
#pragma unroll
  for (int fd = 0; fd < 4; ++fd)
    y0[fd] = __builtin_amdgcn_mfma_f32_16x16x32_bf16(Al[0], xh[fd], y0[fd], 0, 0, 0);
  // refill slot 0 with hh=2
  Ah[0] = *reinterpret_cast<const bf16x8*>(pwh + 2 * hstride);
  Al[0] = *reinterpret_cast<const bf16x8*>(pwl + 2 * hstride);

  // one pipelined step; p = hh&1 (compile-time): compute yC=y<p>, acc from y<1-p>
#define CIN_STEP(hh_expr, yC, yP)                                                 \
  {                                                                               \
    const int hh_ = (hh_expr);                                                    \
    const int p_ = hh_ & 1;                                                       \
    _Pragma("unroll") for (int fd = 0; fd < 4; ++fd) yC[fd] =                     \
        __builtin_amdgcn_mfma_f32_16x16x32_bf16(Ah[p_], xh[fd], kZ, 0, 0, 0);     \
    _Pragma("unroll") for (int fd = 0; fd < 4; ++fd) yC[fd] =                     \
        __builtin_amdgcn_mfma_f32_16x16x32_bf16(Ah[p_], xl[fd], yC[fd], 0, 0, 0); \
    _Pragma("unroll") for (int fd = 0; fd < 4; ++fd) yC[fd] =                     \
        __builtin_amdgcn_mfma_f32_16x16x32_bf16(Al[p_], xh[fd], yC[fd], 0, 0, 0); \
    const size_t roff = (size_t)((hh_ + 2) & (HW - 1)) * hstride;                 \
    Ah[p_] = *reinterpret_cast<const bf16x8*>(pwh + roff);                        \
    Al[p_] = *reinterpret_cast<const bf16x8*>(pwl + roff);                        \
    float hvN[4];                                                                 \
    _Pragma("unroll") for (int fd = 0; fd < 4; ++fd) hvN[fd] =                    \
        hsrc[hh_ * 64 + fd * 16 + cid];                                           \
    _Pragma("unroll") for (int fd = 0; fd < 4; ++fd)                              \
        _Pragma("unroll") for (int r = 0; r < 4; ++r)                             \
            acc[fd][r] = fmaf(hvP[fd], yP[fd][r], acc[fd][r]);                    \
    _Pragma("unroll") for (int fd = 0; fd < 4; ++fd) hvP[fd] = hvN[fd];           \
  }

  // peeled steps 1..3 (prologue covered hh=0)
  CIN_STEP(1, y1, y0)
  CIN_STEP(2, y0, y1)
  CIN_STEP(3, y1, y0)

#pragma unroll 1
  for (int g = 1; g < HW / 4; ++g) {
    const int h0 = g * 4;
    CIN_STEP(h0 + 0, y0, y1)
    CIN_STEP(h0 + 1, y1, y0)
    CIN_STEP(h0 + 2, y0, y1)
    CIN_STEP(h0 + 3, y1, y0)
  }
#undef CIN_STEP

  // epilogue: acc-update for hh = HW-1 (odd -> its y landed in y1)
#pragma unroll
  for (int fd = 0; fd < 4; ++fd)
#pragma unroll
    for (int r = 0; r < 4; ++r) acc[fd][r] = fmaf(hvP[fd], y1[fd][r], acc[fd][r]);
}

// One layer: both k-half waves run mfma_loop over their range; kh=1 dumps raw
// acc into h_next's f-region; kh=0 combines, applies bias+relu, writes h_next
// (unless !WRITE_H) and folds the d-sum into score.
template <int H, bool WRITE_H>
static __device__ __forceinline__ void layer(
    const float* __restrict__ h_src, float* __restrict__ h_next,
    const ushort* __restrict__ Whi, const ushort* __restrict__ Wlo,
    const float* __restrict__ bias, const float* __restrict__ lw,
    const bf16x8 (&xh)[4], const bf16x8 (&xl)[4],
    int f, int kh, int lane, float& score) {
  const int cid = lane & 15;
  const int rg = lane >> 4;
  const int hh0 = kh * (H / 2);

  f32x4 acc[4];
#pragma unroll
  for (int fd = 0; fd < 4; ++fd) acc[fd] = (f32x4){0.f, 0.f, 0.f, 0.f};

  const ushort* pwh = Whi + (((size_t)hh0 * 8 + f) * 64 + lane) * 8;
  const ushort* pwl = Wlo + (((size_t)hh0 * 8 + f) * 64 + lane) * 8;
  mfma_loop<H / 2>(h_src + hh0 * 64, pwh, pwl, xh, xl, cid, acc);

  if (kh) {  // dump raw partial acc into h_next's f-region (dead until combine)
#pragma unroll
    for (int r = 0; r < 4; ++r)
#pragma unroll
      for (int fd = 0; fd < 4; ++fd)
        h_next[(f * 16 + rg * 4 + r) * 64 + fd * 16 + cid] = acc[fd][r];
  }
  __syncthreads();
  if (!kh) {
#pragma unroll
    for (int r = 0; r < 4; ++r) {
      const int o = f * 16 + rg * 4 + r;
      const float bs = bias[o];
      float sd = 0.f;
#pragma unroll
      for (int fd = 0; fd < 4; ++fd) {
        float v = acc[fd][r] + h_next[o * 64 + fd * 16 + cid] + bs;
        v = v > 0.f ? v : 0.f;
        if (WRITE_H) h_next[o * 64 + fd * 16 + cid] = v;
        sd += v;
      }
#pragma unroll
      for (int mk = 1; mk < 16; mk <<= 1) sd += __shfl_xor(sd, mk, 64);
      if (cid == 0) score = fmaf(sd, lw[o], score);
    }
  }
  __syncthreads();
}

__global__ __launch_bounds__(1024) void cin_fused_kernel(
    const float* __restrict__ x0,
    const ushort* __restrict__ Whi0, const ushort* __restrict__ Wlo0,
    const ushort* __restrict__ Whi1, const ushort* __restrict__ Wlo1,
    const ushort* __restrict__ Whi2, const ushort* __restrict__ Wlo2,
    const ushort* __restrict__ Xhi, const ushort* __restrict__ Xlo,
    const float* __restrict__ b0, const float* __restrict__ b1,
    const float* __restrict__ b2, const float* __restrict__ lw,
    const float* __restrict__ lb, float* __restrict__ out) {
  __shared__ float hA[Oo * Dd];  // 32 KB: x0 (L0 in), then L1 out (L2 in)
  __shared__ float hB[Oo * Dd];  // 32 KB: L0 out (L1 in), then L2 scratch+sred
  // total LDS = 65536 B

  const int b = blockIdx.x;
  const int t = threadIdx.x;
  const int lane = t & 63;
  const int w = __builtin_amdgcn_readfirstlane(t >> 6);  // 16 waves
  const int f = w & 7;    // o-frag
  const int kh = w >> 3;  // k-half

  // x0 B-fragments, register-resident throughout
  bf16x8 xh[4], xl[4];
#pragma unroll
  for (int fd = 0; fd < 4; ++fd) {
    size_t off = (((size_t)b * 4 + fd) * 64 + lane) * 8;
    xh[fd] = *reinterpret_cast<const bf16x8*>(Xhi + off);
    xl[fd] = *reinterpret_cast<const bf16x8*>(Xlo + off);
  }

  // stage x0[b] (32x64 f32 = 512 float4) into hA
  if (t < 512)
    reinterpret_cast<float4*>(hA)[t] =
        reinterpret_cast<const float4*>(x0 + (size_t)b * Mm * Dd)[t];
  __syncthreads();

  float score = 0.f;
  layer<32, true>(hA, hB, Whi0, Wlo0, b0, lw, xh, xl, f, kh, lane, score);
  layer<128, true>(hB, hA, Whi1, Wlo1, b1, lw + 128, xh, xl, f, kh, lane, score);
  layer<128, false>(hA, hB, Whi2, Wlo2, b2, lw + 256, xh, xl, f, kh, lane, score);

  // block-wide score reduction (hB scratch dead; layer() ended with a barrier)
#pragma unroll
  for (int mk = 1; mk < 64; mk <<= 1) score += __shfl_xor(score, mk, 64);
  if (lane == 0 && kh == 0) hB[f] = score;
  __syncthreads();
  if (t == 0) {
    float tot = 0.f;
#pragma unroll
    for (int i = 0; i < 8; ++i) tot += hB[i];
    out[b] = tot + lb[0];
  }
}

extern "C" void kernel_launch(void* const* d_in, const int* in_sizes, int n_in,
                              void* d_out, int out_size, void* d_ws, size_t ws_size,
                              hipStream_t stream) {
  const float* x0 = (const float*)d_in[0];
  const float* W0 = (const float*)d_in[1];
  const float* b0 = (const float*)d_in[2];
  const float* W1 = (const float*)d_in[3];
  const float* b1 = (const float*)d_in[4];
  const float* W2 = (const float*)d_in[5];
  const float* b2 = (const float*)d_in[6];
  const float* lw = (const float*)d_in[7];
  const float* lb = (const float*)d_in[8];
  float* out = (float*)d_out;

  // workspace: only the split planes
  ushort* Whi0 = (ushort*)d_ws;
  ushort* Wlo0 = Whi0 + (size_t)32 * 8 * 64 * 8;
  ushort* Whi1 = Wlo0 + (size_t)32 * 8 * 64 * 8;
  ushort* Wlo1 = Whi1 + (size_t)128 * 8 * 64 * 8;
  ushort* Whi2 = Wlo1 + (size_t)128 * 8 * 64 * 8;
  ushort* Wlo2 = Whi2 + (size_t)128 * 8 * 64 * 8;
  ushort* Xhi = Wlo2 + (size_t)128 * 8 * 64 * 8;
  ushort* Xlo = Xhi + (size_t)Bb * 4 * 64 * 8;

  prep_kernel<<<dim3(1088), dim3(256), 0, stream>>>(W0, W1, W2, x0, Whi0, Wlo0,
                                                    Whi1, Wlo1, Whi2, Wlo2, Xhi, Xlo);

  cin_fused_kernel<<<dim3(Bb), dim3(1024), 0, stream>>>(
      x0, Whi0, Wlo0, Whi1, Wlo1, Whi2, Wlo2, Xhi, Xlo, b0, b1, b2, lw, lb, out);
}

// Round 14
// 263.014 us; speedup vs baseline: 3.6327x; 3.6103x over previous
//
#include <hip/hip_runtime.h>

// Fully-fused CIN (16x16x32 MFMA, HW-verified layouts).
//   Y_hh[o,d] = sum_m W[o,hh,m] * x0[b,m,d]      (MFMA, 3-term bf16 split)
//   h_next[o,d] = relu(bias[o] + sum_hh h[hh,d] * Y_hh[o,d])
// Round-13: half-step software pipeline at a LEGAL register budget.
// Evidence: 1024-thread builds always cap at 64 VGPR (r9/r11/r12 -> spills);
// 512-thread (512,2) reached 72 without spills (r5/r8, cap 128). Structure:
// 8 waves (one o-frag each, full K), step hh split into HalfA(fd0,1)/
// HalfB(fd2,3) of 6 MFMAs each; schedule issue-HalfB(e) / consume-yA(e) /
// issue-HalfA(e+1) / consume-yB(e) so every consume trails its producer by
// >=6 MFMAs -> no wait on the MFMA chain. y regs 16 (vs 32 in r11/r12);
// all ring/parity indices compile-time (named regs).
// B=512, M=32, D=64, O=128/layer, H = 32/128/128.

constexpr int Bb = 512, Mm = 32, Dd = 64, Oo = 128;

typedef __attribute__((ext_vector_type(8))) short bf16x8;
typedef __attribute__((ext_vector_type(4))) float f32x4;

static __device__ __forceinline__ ushort f2bf(float f) {
  union { float f; uint u; } v;
  v.f = f;
  uint u = v.u;
  return (ushort)((u + 0x7FFFu + ((u >> 16) & 1u)) >> 16);  // RNE
}
static __device__ __forceinline__ float bf2f(ushort b) {
  union { uint u; float f; } v;
  v.u = (uint)b << 16;
  return v.f;
}

// W[o][hh*32+m] -> A-frag planes [hh][f][lane][j]: o=f*16+(lane&15), m=(lane>>4)*8+j
static __device__ __forceinline__ void wsplit_one(const float* __restrict__ W,
                                                  ushort* __restrict__ Whi,
                                                  ushort* __restrict__ Wlo,
                                                  int H, int t) {
  int l = t & 63, fo = (t >> 6) & 7, hh = t >> 9;
  int o = fo * 16 + (l & 15);
  int m0 = (l >> 4) * 8;
  const float* src = W + (size_t)o * (H * 32) + hh * 32 + m0;
  ushort hi[8], lo[8];
#pragma unroll
  for (int j = 0; j < 8; ++j) {
    float w = src[j];
    ushort h = f2bf(w);
    hi[j] = h;
    lo[j] = f2bf(w - bf2f(h));
  }
  *reinterpret_cast<uint4*>(Whi + (size_t)t * 8) = *reinterpret_cast<uint4*>(hi);
  *reinterpret_cast<uint4*>(Wlo + (size_t)t * 8) = *reinterpret_cast<uint4*>(lo);
}

// x0[b][m][d] -> B-frag planes [b][fd][lane][j]: m=(lane>>4)*8+j, d=fd*16+(lane&15)
static __device__ __forceinline__ void x0split_one(const float* __restrict__ x0,
                                                   ushort* __restrict__ Xhi,
                                                   ushort* __restrict__ Xlo, int t) {
  int l = t & 63, fd = (t >> 6) & 3, b = t >> 8;
  int d = fd * 16 + (l & 15);
  int m0 = (l >> 4) * 8;
  const float* src = x0 + ((size_t)b * Mm + m0) * Dd + d;
  ushort hi[8], lo[8];
#pragma unroll
  for (int j = 0; j < 8; ++j) {
    float w = src[j * Dd];
    ushort h = f2bf(w);
    hi[j] = h;
    lo[j] = f2bf(w - bf2f(h));
  }
  *reinterpret_cast<uint4*>(Xhi + (size_t)t * 8) = *reinterpret_cast<uint4*>(hi);
  *reinterpret_cast<uint4*>(Xlo + (size_t)t * 8) = *reinterpret_cast<uint4*>(lo);
}

__global__ __launch_bounds__(256) void prep_kernel(
    const float* __restrict__ W0, const float* __restrict__ W1,
    const float* __restrict__ W2, const float* __restrict__ x0,
    ushort* __restrict__ Whi0, ushort* __restrict__ Wlo0,
    ushort* __restrict__ Whi1, ushort* __restrict__ Wlo1,
    ushort* __restrict__ Whi2, ushort* __restrict__ Wlo2,
    ushort* __restrict__ Xhi, ushort* __restrict__ Xlo) {
  int t = blockIdx.x * 256 + threadIdx.x;
  if (t < 16384) {
    wsplit_one(W0, Whi0, Wlo0, 32, t);
  } else if (t < 81920) {
    wsplit_one(W1, Whi1, Wlo1, 128, t - 16384);
  } else if (t < 147456) {
    wsplit_one(W2, Whi2, Wlo2, 128, t - 81920);
  } else {
    x0split_one(x0, Xhi, Xlo, t - 147456);
  }
}

// Half-step-pipelined MFMA loop over HW hh-steps (full K range of one wave).
template <int HW>
static __device__ __forceinline__ void mfma_loop(
    const float* __restrict__ hsrc,
    const ushort* __restrict__ pwh, const ushort* __restrict__ pwl,
    const bf16x8 (&xh)[4], const bf16x8 (&xl)[4], int cid, f32x4 (&acc)[4]) {
  static_assert((HW & (HW - 1)) == 0 && HW >= 8, "HW must be pow2 >= 8");
  const size_t hstride = (size_t)8 * 64 * 8;  // ushorts per hh
  const f32x4 kZ = {0.f, 0.f, 0.f, 0.f};

  // A-ring depth 2, named regs: A0 = even steps, A1 = odd steps
  bf16x8 A0h = *reinterpret_cast<const bf16x8*>(pwh);
  bf16x8 A0l = *reinterpret_cast<const bf16x8*>(pwl);
  bf16x8 A1h = *reinterpret_cast<const bf16x8*>(pwh + hstride);
  bf16x8 A1l = *reinterpret_cast<const bf16x8*>(pwl + hstride);

  // h for current step (all 4 fd columns of this lane)
  float hv0 = hsrc[0 * 16 + cid];
  float hv1 = hsrc[1 * 16 + cid];
  float hv2 = hsrc[2 * 16 + cid];
  float hv3 = hsrc[3 * 16 + cid];

  f32x4 yA0, yA1, yB0, yB1;

  // 6 MFMAs: two interleaved 3-term chains for fragment columns f0_, f1_
#define CIN_HALF(Ah_, Al_, y0_, y1_, f0_, f1_)                                 \
  y0_ = __builtin_amdgcn_mfma_f32_16x16x32_bf16(Ah_, xh[f0_], kZ, 0, 0, 0);    \
  y1_ = __builtin_amdgcn_mfma_f32_16x16x32_bf16(Ah_, xh[f1_], kZ, 0, 0, 0);    \
  y0_ = __builtin_amdgcn_mfma_f32_16x16x32_bf16(Ah_, xl[f0_], y0_, 0, 0, 0);   \
  y1_ = __builtin_amdgcn_mfma_f32_16x16x32_bf16(Ah_, xl[f1_], y1_, 0, 0, 0);   \
  y0_ = __builtin_amdgcn_mfma_f32_16x16x32_bf16(Al_, xh[f0_], y0_, 0, 0, 0);   \
  y1_ = __builtin_amdgcn_mfma_f32_16x16x32_bf16(Al_, xh[f1_], y1_, 0, 0, 0);

#define CIN_CONSUME(y0_, y1_, h0_, h1_, a0_, a1_)                              \
  _Pragma("unroll") for (int r = 0; r < 4; ++r) {                              \
    acc[a0_][r] = fmaf(h0_, y0_[r], acc[a0_][r]);                              \
    acc[a1_][r] = fmaf(h1_, y1_[r], acc[a1_][r]);                              \
  }

  CIN_HALF(A0h, A0l, yA0, yA1, 0, 1)  // prologue: HalfA(0)

#pragma unroll 1
  for (int hh2 = 0; hh2 < HW / 2; ++hh2) {
    const int e = 2 * hh2;
    // ---- even step e ----
    CIN_HALF(A0h, A0l, yB0, yB1, 2, 3)         // HalfB(e)
    CIN_CONSUME(yA0, yA1, hv0, hv1, 0, 1)      // yA(e), issued >=1 half ago
    {
      const size_t ro = (size_t)((e + 2) & (HW - 1)) * hstride;  // refill even slot
      A0h = *reinterpret_cast<const bf16x8*>(pwh + ro);
      A0l = *reinterpret_cast<const bf16x8*>(pwl + ro);
    }
    float n0 = hsrc[(e + 1) * 64 + 0 * 16 + cid];
    float n1 = hsrc[(e + 1) * 64 + 1 * 16 + cid];
    float n2 = hsrc[(e + 1) * 64 + 2 * 16 + cid];
    float n3 = hsrc[(e + 1) * 64 + 3 * 16 + cid];
    CIN_HALF(A1h, A1l, yA0, yA1, 0, 1)         // HalfA(e+1)
    CIN_CONSUME(yB0, yB1, hv2, hv3, 2, 3)      // yB(e)
    hv0 = n0; hv1 = n1; hv2 = n2; hv3 = n3;
    // ---- odd step e+1 ----
    CIN_HALF(A1h, A1l, yB0, yB1, 2, 3)         // HalfB(e+1)
    CIN_CONSUME(yA0, yA1, hv0, hv1, 0, 1)      // yA(e+1)
    {
      const size_t ro = (size_t)((e + 3) & (HW - 1)) * hstride;  // refill odd slot
      A1h = *reinterpret_cast<const bf16x8*>(pwh + ro);
      A1l = *reinterpret_cast<const bf16x8*>(pwl + ro);
    }
    const int nx = (e + 2) & (HW - 1);  // wraps to 0 on last pair (benign)
    n0 = hsrc[nx * 64 + 0 * 16 + cid];
    n1 = hsrc[nx * 64 + 1 * 16 + cid];
    n2 = hsrc[nx * 64 + 2 * 16 + cid];
    n3 = hsrc[nx * 64 + 3 * 16 + cid];
    CIN_HALF(A0h, A0l, yA0, yA1, 0, 1)         // HalfA(e+2); garbage on last pair,
    CIN_CONSUME(yB0, yB1, hv2, hv3, 2, 3)      //   never consumed (6 wasted MFMAs)
    hv0 = n0; hv1 = n1; hv2 = n2; hv3 = n3;
  }
#undef CIN_HALF
#undef CIN_CONSUME
}

// One layer for one wave: o-tile f*16..f*16+15, full K. h from h_src (LDS, or
// global x0 for layer 0); relu output to LDS unless !WRITE_H; score folded.
template <int H, bool WRITE_H>
static __device__ __forceinline__ void run_layer(
    const float* __restrict__ h_src, float* __restrict__ h_next,
    const ushort* __restrict__ Whi, const ushort* __restrict__ Wlo,
    const float* __restrict__ bias, const float* __restrict__ lw,
    const bf16x8 (&xh)[4], const bf16x8 (&xl)[4],
    int f, int lane, float& score) {
  const int cid = lane & 15;
  const int rg = lane >> 4;

  f32x4 acc[4];
#pragma unroll
  for (int fd = 0; fd < 4; ++fd) acc[fd] = (f32x4){0.f, 0.f, 0.f, 0.f};

  const ushort* pwh = Whi + ((size_t)f * 64 + lane) * 8;
  const ushort* pwl = Wlo + ((size_t)f * 64 + lane) * 8;
  mfma_loop<H>(h_src, pwh, pwl, xh, xl, cid, acc);

  // epilogue: bias + relu, write h_next (LDS), fold d-sum into score
#pragma unroll
  for (int r = 0; r < 4; ++r) {
    const int o = f * 16 + rg * 4 + r;
    const float bs = bias[o];
    float sd = 0.f;
#pragma unroll
    for (int fd = 0; fd < 4; ++fd) {
      float v = acc[fd][r] + bs;
      v = v > 0.f ? v : 0.f;
      if (WRITE_H) h_next[o * 64 + fd * 16 + cid] = v;
      sd += v;
    }
#pragma unroll
    for (int mk = 1; mk < 16; mk <<= 1) sd += __shfl_xor(sd, mk, 64);
    if (cid == 0) score = fmaf(sd, lw[o], score);
  }
}

__global__ __launch_bounds__(512, 2) void cin_fused_kernel(
    const float* __restrict__ x0,
    const ushort* __restrict__ Whi0, const ushort* __restrict__ Wlo0,
    const ushort* __restrict__ Whi1, const ushort* __restrict__ Wlo1,
    const ushort* __restrict__ Whi2, const ushort* __restrict__ Wlo2,
    const ushort* __restrict__ Xhi, const ushort* __restrict__ Xlo,
    const float* __restrict__ b0, const float* __restrict__ b1,
    const float* __restrict__ b2, const float* __restrict__ lw,
    const float* __restrict__ lb, float* __restrict__ out) {
  __shared__ float hA[Oo * Dd];  // 32 KB: layer-1 output
  __shared__ float hB[Oo * Dd];  // 32 KB: layer-0 output; [0..7] reused as sred
  // total LDS = 65536 B

  const int b = blockIdx.x;
  const int t = threadIdx.x;
  const int lane = t & 63;
  const int f = __builtin_amdgcn_readfirstlane(t >> 6);  // wave id = o-frag

  // x0 B-fragments, register-resident throughout
  bf16x8 xh[4], xl[4];
#pragma unroll
  for (int fd = 0; fd < 4; ++fd) {
    size_t off = (((size_t)b * 4 + fd) * 64 + lane) * 8;
    xh[fd] = *reinterpret_cast<const bf16x8*>(Xhi + off);
    xl[fd] = *reinterpret_cast<const bf16x8*>(Xlo + off);
  }

  float score = 0.f;
  // layer 0: h = x0[b] read directly from global (8 KB, L1/L2-hot)
  run_layer<32, true>(x0 + (size_t)b * Mm * Dd, hB, Whi0, Wlo0, b0, lw,
                      xh, xl, f, lane, score);
  __syncthreads();
  run_layer<128, true>(hB, hA, Whi1, Wlo1, b1, lw + 128, xh, xl, f, lane, score);
  __syncthreads();
  run_layer<128, false>(hA, hB, Whi2, Wlo2, b2, lw + 256, xh, xl, f, lane, score);

  // block-wide score reduction (hB dead after layer-2 start)
#pragma unroll
  for (int mk = 1; mk < 64; mk <<= 1) score += __shfl_xor(score, mk, 64);
  if (lane == 0) hB[f] = score;
  __syncthreads();
  if (t == 0) {
    float tot = 0.f;
#pragma unroll
    for (int i = 0; i < 8; ++i) tot += hB[i];
    out[b] = tot + lb[0];
  }
}

extern "C" void kernel_launch(void* const* d_in, const int* in_sizes, int n_in,
                              void* d_out, int out_size, void* d_ws, size_t ws_size,
                              hipStream_t stream) {
  const float* x0 = (const float*)d_in[0];
  const float* W0 = (const float*)d_in[1];
  const float* b0 = (const float*)d_in[2];
  const float* W1 = (const float*)d_in[3];
  const float* b1 = (const float*)d_in[4];
  const float* W2 = (const float*)d_in[5];
  const float* b2 = (const float*)d_in[6];
  const float* lw = (const float*)d_in[7];
  const float* lb = (const float*)d_in[8];
  float* out = (float*)d_out;

  // workspace: only the split planes
  ushort* Whi0 = (ushort*)d_ws;
  ushort* Wlo0 = Whi0 + (size_t)32 * 8 * 64 * 8;
  ushort* Whi1 = Wlo0 + (size_t)32 * 8 * 64 * 8;
  ushort* Wlo1 = Whi1 + (size_t)128 * 8 * 64 * 8;
  ushort* Whi2 = Wlo1 + (size_t)128 * 8 * 64 * 8;
  ushort* Wlo2 = Whi2 + (size_t)128 * 8 * 64 * 8;
  ushort* Xhi = Wlo2 + (size_t)128 * 8 * 64 * 8;
  ushort* Xlo = Xhi + (size_t)Bb * 4 * 64 * 8;

  prep_kernel<<<dim3(1088), dim3(256), 0, stream>>>(W0, W1, W2, x0, Whi0, Wlo0,
                                                    Whi1, Wlo1, Whi2, Wlo2, Xhi, Xlo);

  cin_fused_kernel<<<dim3(Bb), dim3(512), 0, stream>>>(
      x0, Whi0, Wlo0, Whi1, Wlo1, Whi2, Wlo2, Xhi, Xlo, b0, b1, b2, lw, lb, out);
}